// Round 2
// baseline (427.999 us; speedup 1.0000x reference)
//
#include <hip/hip_runtime.h>
#include <hip/hip_cooperative_groups.h>
#include <math.h>

namespace cg = cooperative_groups;

// Problem constants (match reference)
static constexpr int   kC   = 1000;    // NUM_CLASSES
static constexpr int   kD   = 256;     // EMBED_DIM
static constexpr float kMom = 0.995f;  // MOMENTUM
static constexpr float kEps = 1e-12f;  // F.normalize eps

// ---- block-wide sum over 256 threads (4 waves of 64) ----
__device__ __forceinline__ float block_sum256(float v) {
    __shared__ float lds[4];
    #pragma unroll
    for (int off = 32; off > 0; off >>= 1) v += __shfl_down(v, off, 64);
    __syncthreads();                       // protect lds from prior call's reads
    if ((threadIdx.x & 63) == 0) lds[threadIdx.x >> 6] = v;
    __syncthreads();
    return lds[0] + lds[1] + lds[2] + lds[3];
}

// ---- per-class gather-sum + fused normalize/EMA epilogue ----
// block = 256 threads (4 waves); wave w takes rows w, w+4, w+8, ... of class c.
// Each row is read as ONE float4/lane load: 16 B x 64 lanes = the full 1 KB row.
__device__ __forceinline__ void class_reduce_finalize(
    int c,
    const float* __restrict__ z, const float* __restrict__ protos,
    const int* __restrict__ initialized, const int* __restrict__ counts,
    const int* __restrict__ starts, const int* __restrict__ idx,
    float* __restrict__ out)
{
    __shared__ int   sh_idx[1024];
    __shared__ float sh_part[4][256];

    const int tid  = threadIdx.x;
    const int wave = tid >> 6;
    const int lane = tid & 63;

    const int cnt   = counts[c];
    const int start = starts[c];

    float4 acc0 = make_float4(0.f, 0.f, 0.f, 0.f);
    float4 acc1 = make_float4(0.f, 0.f, 0.f, 0.f);

    for (int chunk = 0; chunk < cnt; chunk += 1024) {
        const int m = min(1024, cnt - chunk);
        __syncthreads();                         // sh_idx reuse guard
        for (int j = tid; j < m; j += 256) sh_idx[j] = idx[start + chunk + j];
        __syncthreads();

        int r = wave;
        // 4 independent 1KB-row loads in flight per wave
        for (; r + 12 < m; r += 16) {
            const int i0 = sh_idx[r];
            const int i1 = sh_idx[r + 4];
            const int i2 = sh_idx[r + 8];
            const int i3 = sh_idx[r + 12];
            const float4 a = ((const float4*)(z + (size_t)i0 * kD))[lane];
            const float4 b = ((const float4*)(z + (size_t)i1 * kD))[lane];
            const float4 d2 = ((const float4*)(z + (size_t)i2 * kD))[lane];
            const float4 e2 = ((const float4*)(z + (size_t)i3 * kD))[lane];
            acc0.x += a.x; acc0.y += a.y; acc0.z += a.z; acc0.w += a.w;
            acc1.x += b.x; acc1.y += b.y; acc1.z += b.z; acc1.w += b.w;
            acc0.x += d2.x; acc0.y += d2.y; acc0.z += d2.z; acc0.w += d2.w;
            acc1.x += e2.x; acc1.y += e2.y; acc1.z += e2.z; acc1.w += e2.w;
        }
        for (; r < m; r += 4) {
            const int i0 = sh_idx[r];
            const float4 a = ((const float4*)(z + (size_t)i0 * kD))[lane];
            acc0.x += a.x; acc0.y += a.y; acc0.z += a.z; acc0.w += a.w;
        }
    }
    acc0.x += acc1.x; acc0.y += acc1.y; acc0.z += acc1.z; acc0.w += acc1.w;

    __syncthreads();                             // sh_idx readers done
    ((float4*)&sh_part[wave][lane * 4])[0] = acc0;
    __syncthreads();

    const int d = tid;
    const float sum = sh_part[0][d] + sh_part[1][d] + sh_part[2][d] + sh_part[3][d];

    const float mean   = sum / fmaxf((float)cnt, 1.0f);
    const float nrm    = sqrtf(block_sum256(mean * mean));
    const float mean_n = mean / fmaxf(nrm, kEps);

    const float p    = protos[c * kD + d];
    const float e    = kMom * p + (1.0f - kMom) * mean_n;
    const float nrm2 = sqrtf(block_sum256(e * e));
    const float ema  = e / fmaxf(nrm2, kEps);

    const float cand = (initialized[c] != 0) ? ema : mean_n;
    out[c * kD + d] = (cnt > 0) ? cand : p;
}

// ================= fused cooperative kernel: all 5 stages, 1 launch =========
__global__ void __launch_bounds__(256, 4)
k_fused(const float* __restrict__ z, const float* __restrict__ protos,
        const int* __restrict__ initialized, const int* __restrict__ labels,
        int n, int* __restrict__ counts, int* __restrict__ starts,
        int* __restrict__ cursor, int* __restrict__ idx,
        float* __restrict__ out)
{
    cg::grid_group grid = cg::this_grid();
    __shared__ int part[256];

    const int tid = threadIdx.x;
    const int gid = blockIdx.x * 256 + tid;
    const int gsz = gridDim.x * 256;

    // stage 0: zero counts
    for (int c = gid; c < kC; c += gsz) counts[c] = 0;
    grid.sync();

    // stage 1: histogram (cache this thread's label in a register)
    const int lab = (gid < n) ? labels[gid] : -1;
    if (lab >= 0) atomicAdd(&counts[lab], 1);
    for (int i = gid + gsz; i < n; i += gsz) atomicAdd(&counts[labels[i]], 1);
    grid.sync();

    // stage 2: exclusive scan (block 0 only; 4 values per thread)
    if (blockIdx.x == 0) {
        const int base = tid * 4;
        int v0 = (base + 0 < kC) ? counts[base + 0] : 0;
        int v1 = (base + 1 < kC) ? counts[base + 1] : 0;
        int v2 = (base + 2 < kC) ? counts[base + 2] : 0;
        int v3 = (base + 3 < kC) ? counts[base + 3] : 0;
        const int tsum = v0 + v1 + v2 + v3;
        part[tid] = tsum;
        __syncthreads();
        for (int off = 1; off < 256; off <<= 1) {
            const int add = (tid >= off) ? part[tid - off] : 0;
            __syncthreads();
            part[tid] += add;
            __syncthreads();
        }
        int ex = part[tid] - tsum;               // exclusive prefix of chunk
        if (base + 0 < kC) { starts[base + 0] = ex; cursor[base + 0] = ex; } ex += v0;
        if (base + 1 < kC) { starts[base + 1] = ex; cursor[base + 1] = ex; } ex += v1;
        if (base + 2 < kC) { starts[base + 2] = ex; cursor[base + 2] = ex; } ex += v2;
        if (base + 3 < kC) { starts[base + 3] = ex; cursor[base + 3] = ex; }
    }
    grid.sync();

    // stage 3: scatter row indices into class-sorted order
    if (lab >= 0) { const int p = atomicAdd(&cursor[lab], 1); idx[p] = gid; }
    for (int i = gid + gsz; i < n; i += gsz) {
        const int p = atomicAdd(&cursor[labels[i]], 1);
        idx[p] = i;
    }
    grid.sync();

    // stage 4: one block per class
    if (blockIdx.x < kC)
        class_reduce_finalize(blockIdx.x, z, protos, initialized,
                              counts, starts, idx, out);
}

// ================= fallback multi-launch path ===============================
__global__ void k_hist(const int* __restrict__ labels, int n, int* __restrict__ counts) {
    const int i = blockIdx.x * blockDim.x + threadIdx.x;
    if (i < n) atomicAdd(&counts[labels[i]], 1);
}

__global__ void k_scan(const int* __restrict__ counts,
                       int* __restrict__ starts, int* __restrict__ cursor) {
    __shared__ int buf[1024];
    const int t = threadIdx.x;
    const int v = (t < kC) ? counts[t] : 0;
    buf[t] = v;
    __syncthreads();
    for (int off = 1; off < 1024; off <<= 1) {
        const int add = (t >= off) ? buf[t - off] : 0;
        __syncthreads();
        buf[t] += add;
        __syncthreads();
    }
    if (t < kC) {
        const int ex = buf[t] - v;
        starts[t] = ex;
        cursor[t] = ex;
    }
}

__global__ void k_scatter(const int* __restrict__ labels, int n,
                          int* __restrict__ cursor, int* __restrict__ idx) {
    const int i = blockIdx.x * blockDim.x + threadIdx.x;
    if (i < n) {
        const int p = atomicAdd(&cursor[labels[i]], 1);
        idx[p] = i;
    }
}

__global__ void __launch_bounds__(256, 4)
k_reduce_v2(const float* __restrict__ z, const float* __restrict__ protos,
            const int* __restrict__ initialized, const int* __restrict__ counts,
            const int* __restrict__ starts, const int* __restrict__ idx,
            float* __restrict__ out) {
    class_reduce_finalize(blockIdx.x, z, protos, initialized, counts, starts, idx, out);
}

extern "C" void kernel_launch(void* const* d_in, const int* in_sizes, int n_in,
                              void* d_out, int out_size, void* d_ws, size_t ws_size,
                              hipStream_t stream) {
    const float* z           = (const float*)d_in[0];
    const float* protos      = (const float*)d_in[1];
    const int*   initialized = (const int*)d_in[2];
    const int*   labels      = (const int*)d_in[3];
    int n = in_sizes[3];               // N (labels count)
    float* out = (float*)d_out;

    int* ws     = (int*)d_ws;
    int* counts = ws;                  // [kC]
    int* starts = ws + 1024;           // [kC]
    int* cursor = ws + 2048;           // [kC]
    int* idx    = ws + 3072;           // [N]

    // single cooperative launch: hist + scan + scatter + reduce fused
    void* args[] = { (void*)&z, (void*)&protos, (void*)&initialized, (void*)&labels,
                     (void*)&n, (void*)&counts, (void*)&starts, (void*)&cursor,
                     (void*)&idx, (void*)&out };
    hipError_t err = hipLaunchCooperativeKernel((const void*)k_fused,
                                                dim3(kC), dim3(256),
                                                args, 0, stream);
    if (err == hipSuccess) return;

    // fallback: classic multi-launch pipeline
    hipMemsetAsync(counts, 0, kC * sizeof(int), stream);
    const int blocks = (n + 255) / 256;
    k_hist   <<<blocks, 256, 0, stream>>>(labels, n, counts);
    k_scan   <<<1, 1024, 0, stream>>>(counts, starts, cursor);
    k_scatter<<<blocks, 256, 0, stream>>>(labels, n, cursor, idx);
    k_reduce_v2<<<kC, kD, 0, stream>>>(z, protos, initialized,
                                       counts, starts, idx, out);
}

// Round 3
// 62.282 us; speedup vs baseline: 6.8719x; 6.8719x over previous
//
#include <hip/hip_runtime.h>
#include <math.h>

// Problem constants (match reference)
static constexpr int   kC   = 1000;    // NUM_CLASSES
static constexpr int   kD   = 256;     // EMBED_DIM
static constexpr int   kCap = 1024;    // per-class index bin capacity
static constexpr float kMom = 0.995f;  // MOMENTUM
static constexpr float kEps = 1e-12f;  // F.normalize eps

// ---- block-wide sum over 256 threads (4 waves of 64) ----
__device__ __forceinline__ float block_sum256(float v) {
    __shared__ float lds[4];
    #pragma unroll
    for (int off = 32; off > 0; off >>= 1) v += __shfl_down(v, off, 64);
    __syncthreads();                       // protect lds from prior call's reads
    if ((threadIdx.x & 63) == 0) lds[threadIdx.x >> 6] = v;
    __syncthreads();
    return lds[0] + lds[1] + lds[2] + lds[3];
}

// ---- pass 1: scatter row indices into fixed-capacity class bins ----
// (no histogram, no scan; one pass over labels)
__global__ void k_scatter(const float* __restrict__ z,
                          const int* __restrict__ labels, int n,
                          int* __restrict__ cnt, int* __restrict__ idx,
                          float* __restrict__ sums_x) {
    const int i = blockIdx.x * 256 + threadIdx.x;
    if (i >= n) return;
    const int lab = labels[i];
    const int p = atomicAdd(&cnt[lab], 1);
    if (p < kCap) {
        idx[(size_t)lab * kCap + p] = i;
    } else {
        // overflow valve (statistically never taken): fold row into sums_x
        const float* row = z + (size_t)i * kD;
        float* sx = sums_x + (size_t)lab * kD;
        for (int d = 0; d < kD; ++d) atomicAdd(&sx[d], row[d]);
    }
}

// ---- pass 2: per-class gather-sum + fused normalize/EMA epilogue ----
// one block (4 waves) per class; each row read = ONE float4/lane -> full 1 KB row.
// 8 rows in flight per wave to cover HBM latency.
__global__ void __launch_bounds__(256, 4)
k_reduce(const float* __restrict__ z, const float* __restrict__ protos,
         const int* __restrict__ initialized, const int* __restrict__ cnt,
         const int* __restrict__ idx, const float* __restrict__ sums_x,
         float* __restrict__ out) {
    __shared__ int   sh_idx[kCap];
    __shared__ float sh_part[4][kD];

    const int c    = blockIdx.x;
    const int tid  = threadIdx.x;
    const int wave = tid >> 6;
    const int lane = tid & 63;

    const int cntc = cnt[c];
    const int m    = min(cntc, kCap);
    const int* __restrict__ cidx = idx + (size_t)c * kCap;

    // stage the whole class's index list once (<= 4 KB)
    for (int j = tid; j < m; j += 256) sh_idx[j] = cidx[j];
    __syncthreads();

    float4 acc0 = make_float4(0.f, 0.f, 0.f, 0.f);
    float4 acc1 = make_float4(0.f, 0.f, 0.f, 0.f);

    int r = wave;
    for (; r + 28 < m; r += 32) {           // 8 independent 1KB rows in flight
        const int i0 = sh_idx[r +  0]; const int i1 = sh_idx[r +  4];
        const int i2 = sh_idx[r +  8]; const int i3 = sh_idx[r + 12];
        const int i4 = sh_idx[r + 16]; const int i5 = sh_idx[r + 20];
        const int i6 = sh_idx[r + 24]; const int i7 = sh_idx[r + 28];
        const float4 a0 = ((const float4*)(z + (size_t)i0 * kD))[lane];
        const float4 a1 = ((const float4*)(z + (size_t)i1 * kD))[lane];
        const float4 a2 = ((const float4*)(z + (size_t)i2 * kD))[lane];
        const float4 a3 = ((const float4*)(z + (size_t)i3 * kD))[lane];
        const float4 a4 = ((const float4*)(z + (size_t)i4 * kD))[lane];
        const float4 a5 = ((const float4*)(z + (size_t)i5 * kD))[lane];
        const float4 a6 = ((const float4*)(z + (size_t)i6 * kD))[lane];
        const float4 a7 = ((const float4*)(z + (size_t)i7 * kD))[lane];
        acc0.x += a0.x + a1.x; acc0.y += a0.y + a1.y;
        acc0.z += a0.z + a1.z; acc0.w += a0.w + a1.w;
        acc1.x += a2.x + a3.x; acc1.y += a2.y + a3.y;
        acc1.z += a2.z + a3.z; acc1.w += a2.w + a3.w;
        acc0.x += a4.x + a5.x; acc0.y += a4.y + a5.y;
        acc0.z += a4.z + a5.z; acc0.w += a4.w + a5.w;
        acc1.x += a6.x + a7.x; acc1.y += a6.y + a7.y;
        acc1.z += a6.z + a7.z; acc1.w += a6.w + a7.w;
    }
    for (; r < m; r += 4) {
        const float4 a = ((const float4*)(z + (size_t)sh_idx[r] * kD))[lane];
        acc0.x += a.x; acc0.y += a.y; acc0.z += a.z; acc0.w += a.w;
    }
    acc0.x += acc1.x; acc0.y += acc1.y; acc0.z += acc1.z; acc0.w += acc1.w;

    ((float4*)&sh_part[wave][lane * 4])[0] = acc0;
    __syncthreads();

    const int d = tid;
    const float sum = sh_part[0][d] + sh_part[1][d] + sh_part[2][d] + sh_part[3][d]
                    + sums_x[(size_t)c * kD + d];

    const float mean   = sum / fmaxf((float)cntc, 1.0f);
    const float nrm    = sqrtf(block_sum256(mean * mean));
    const float mean_n = mean / fmaxf(nrm, kEps);

    const float p    = protos[c * kD + d];
    const float e    = kMom * p + (1.0f - kMom) * mean_n;
    const float nrm2 = sqrtf(block_sum256(e * e));
    const float ema  = e / fmaxf(nrm2, kEps);

    const float cand = (initialized[c] != 0) ? ema : mean_n;
    out[c * kD + d] = (cntc > 0) ? cand : p;
}

// ================= fallback path (tiny ws): atomics into d_out ==============
__global__ void k_atomic_accum(const float* __restrict__ z,
                               const int* __restrict__ labels, int n,
                               float* __restrict__ sums, int* __restrict__ counts) {
    const int i = blockIdx.x;
    const int d = threadIdx.x;
    if (i >= n) return;
    const int lab = labels[i];
    atomicAdd(&sums[lab * kD + d], z[i * kD + d]);
    if (d == 0) atomicAdd(&counts[lab], 1);
}

__global__ void k_finalize_from_sums(const float* __restrict__ protos,
                                     const int* __restrict__ initialized,
                                     const int* __restrict__ counts,
                                     float* __restrict__ out) {
    const int c = blockIdx.x;
    const int d = threadIdx.x;
    const int cntc = counts[c];
    const float sum = out[c * kD + d];

    const float mean   = sum / fmaxf((float)cntc, 1.0f);
    const float nrm    = sqrtf(block_sum256(mean * mean));
    const float mean_n = mean / fmaxf(nrm, kEps);

    const float p    = protos[c * kD + d];
    const float e    = kMom * p + (1.0f - kMom) * mean_n;
    const float nrm2 = sqrtf(block_sum256(e * e));
    const float ema  = e / fmaxf(nrm2, kEps);

    const float cand = (initialized[c] != 0) ? ema : mean_n;
    out[c * kD + d] = (cntc > 0) ? cand : p;
}

extern "C" void kernel_launch(void* const* d_in, const int* in_sizes, int n_in,
                              void* d_out, int out_size, void* d_ws, size_t ws_size,
                              hipStream_t stream) {
    const float* z           = (const float*)d_in[0];
    const float* protos      = (const float*)d_in[1];
    const int*   initialized = (const int*)d_in[2];
    const int*   labels      = (const int*)d_in[3];
    const int n = in_sizes[3];          // N (labels count)
    float* out = (float*)d_out;

    // ws layout (4-byte units): [cnt: 1024][sums_x: kC*kD][idx: kC*kCap]
    int*   ws     = (int*)d_ws;
    int*   cnt    = ws;                         // [1024]
    float* sums_x = (float*)(ws + 1024);        // [kC*kD]
    int*   idx    = ws + 1024 + kC * kD;        // [kC*kCap]
    const size_t need = (size_t)(1024 + kC * kD + kC * kCap) * sizeof(int);

    if (ws_size >= need) {
        // zero cnt + sums_x in one contiguous memset (~1 MB)
        hipMemsetAsync(ws, 0, (size_t)(1024 + kC * kD) * sizeof(int), stream);
        const int blocks = (n + 255) / 256;
        k_scatter<<<blocks, 256, 0, stream>>>(z, labels, n, cnt, idx, sums_x);
        k_reduce <<<kC, kD, 0, stream>>>(z, protos, initialized, cnt, idx,
                                         sums_x, out);
    } else {
        // fallback: accumulate sums directly in d_out with float atomics
        int* counts = ws;               // 4 KB
        hipMemsetAsync(counts, 0, kC * sizeof(int), stream);
        hipMemsetAsync(out, 0, (size_t)kC * kD * sizeof(float), stream);
        k_atomic_accum<<<n, kD, 0, stream>>>(z, labels, n, out, counts);
        k_finalize_from_sums<<<kC, kD, 0, stream>>>(protos, initialized, counts, out);
    }
}

// Round 5
// 61.596 us; speedup vs baseline: 6.9485x; 1.0111x over previous
//
#include <hip/hip_runtime.h>
#include <math.h>

// Problem constants (match reference)
static constexpr int   kC   = 1000;    // NUM_CLASSES
static constexpr int   kD   = 256;     // EMBED_DIM
static constexpr int   kCap = 1024;    // per-class index bin capacity
static constexpr float kMom = 0.995f;  // MOMENTUM
static constexpr float kEps = 1e-12f;  // F.normalize eps

typedef float f32x4 __attribute__((ext_vector_type(4)));

__device__ __forceinline__ f32x4 nt_load4(const float* p) {
    return __builtin_nontemporal_load((const f32x4*)p);
}

// ---- block-wide sum over 256 threads (4 waves of 64) ----
__device__ __forceinline__ float block_sum256(float v) {
    __shared__ float lds[4];
    #pragma unroll
    for (int off = 32; off > 0; off >>= 1) v += __shfl_down(v, off, 64);
    __syncthreads();                       // protect lds from prior call's reads
    if ((threadIdx.x & 63) == 0) lds[threadIdx.x >> 6] = v;
    __syncthreads();
    return lds[0] + lds[1] + lds[2] + lds[3];
}

// ---- pass 1: scatter row indices into fixed-capacity class bins ----
// Overflow (statistically never: counts ~ Poisson(131), cap 1024) goes to a
// global (label,row) list; sum(staged)+sum(overflow) covers every row of the
// class regardless of atomic claim order.
__global__ void k_scatter(const int* __restrict__ labels, int n,
                          int* __restrict__ cnt, int* __restrict__ idx,
                          int* __restrict__ ovf /* [0]=count, then pairs */) {
    const int i = blockIdx.x * 256 + threadIdx.x;
    if (i >= n) return;
    const int lab = labels[i];
    const int p = atomicAdd(&cnt[lab], 1);
    if (p < kCap) {
        idx[(size_t)lab * kCap + p] = i;
    } else {
        const int q = atomicAdd(&ovf[0], 1);   // list sized 2N: cannot overflow
        ovf[1 + 2 * q] = lab;
        ovf[2 + 2 * q] = i;
    }
}

// ---- pass 2: per-class gather-sum + fused normalize/EMA epilogue ----
// one block (4 waves) per class; each row read = ONE float4/lane -> full 1 KB
// row in a single wave instruction. 8 rows in flight per wave.
__global__ void __launch_bounds__(256, 4)
k_reduce(const float* __restrict__ z, const float* __restrict__ protos,
         const int* __restrict__ initialized, const int* __restrict__ cnt,
         const int* __restrict__ idx, const int* __restrict__ ovf,
         float* __restrict__ out) {
    __shared__ int   sh_idx[kCap];
    __shared__ float sh_part[4][kD];

    const int c    = blockIdx.x;
    const int tid  = threadIdx.x;
    const int wave = tid >> 6;
    const int lane = tid & 63;

    const int cntc = cnt[c];
    const int m    = min(cntc, kCap);
    const int* __restrict__ cidx = idx + (size_t)c * kCap;

    // stage the whole class's index list once (<= 4 KB)
    for (int j = tid; j < m; j += 256) sh_idx[j] = cidx[j];
    __syncthreads();

    f32x4 acc0 = {0.f, 0.f, 0.f, 0.f};
    f32x4 acc1 = {0.f, 0.f, 0.f, 0.f};

    int r = wave;
    for (; r + 28 < m; r += 32) {           // 8 independent 1KB rows in flight
        const int i0 = sh_idx[r +  0]; const int i1 = sh_idx[r +  4];
        const int i2 = sh_idx[r +  8]; const int i3 = sh_idx[r + 12];
        const int i4 = sh_idx[r + 16]; const int i5 = sh_idx[r + 20];
        const int i6 = sh_idx[r + 24]; const int i7 = sh_idx[r + 28];
        const f32x4 a0 = nt_load4(z + (size_t)i0 * kD + lane * 4);
        const f32x4 a1 = nt_load4(z + (size_t)i1 * kD + lane * 4);
        const f32x4 a2 = nt_load4(z + (size_t)i2 * kD + lane * 4);
        const f32x4 a3 = nt_load4(z + (size_t)i3 * kD + lane * 4);
        const f32x4 a4 = nt_load4(z + (size_t)i4 * kD + lane * 4);
        const f32x4 a5 = nt_load4(z + (size_t)i5 * kD + lane * 4);
        const f32x4 a6 = nt_load4(z + (size_t)i6 * kD + lane * 4);
        const f32x4 a7 = nt_load4(z + (size_t)i7 * kD + lane * 4);
        acc0 += a0 + a1;
        acc1 += a2 + a3;
        acc0 += a4 + a5;
        acc1 += a6 + a7;
    }
    for (; r < m; r += 4) {
        acc0 += nt_load4(z + (size_t)sh_idx[r] * kD + lane * 4);
    }
    acc0 += acc1;

    ((f32x4*)&sh_part[wave][lane * 4])[0] = acc0;
    __syncthreads();

    const int d = tid;
    float sum = sh_part[0][d] + sh_part[1][d] + sh_part[2][d] + sh_part[3][d];

    // cold path: fold in overflow rows (ovf[0]==0 in practice)
    const int novf = ovf[0];
    if (novf > 0) {
        for (int j = 0; j < novf; ++j) {
            if (ovf[1 + 2 * j] == c) sum += z[(size_t)ovf[2 + 2 * j] * kD + d];
        }
    }

    const float mean   = sum / fmaxf((float)cntc, 1.0f);
    const float nrm    = sqrtf(block_sum256(mean * mean));
    const float mean_n = mean / fmaxf(nrm, kEps);

    const float p    = protos[c * kD + d];
    const float e    = kMom * p + (1.0f - kMom) * mean_n;
    const float nrm2 = sqrtf(block_sum256(e * e));
    const float ema  = e / fmaxf(nrm2, kEps);

    const float cand = (initialized[c] != 0) ? ema : mean_n;
    __builtin_nontemporal_store((cntc > 0) ? cand : p, &out[c * kD + d]);
}

// ================= fallback path (tiny ws): atomics into d_out ==============
__global__ void k_atomic_accum(const float* __restrict__ z,
                               const int* __restrict__ labels, int n,
                               float* __restrict__ sums, int* __restrict__ counts) {
    const int i = blockIdx.x;
    const int d = threadIdx.x;
    if (i >= n) return;
    const int lab = labels[i];
    atomicAdd(&sums[lab * kD + d], z[i * kD + d]);
    if (d == 0) atomicAdd(&counts[lab], 1);
}

__global__ void k_finalize_from_sums(const float* __restrict__ protos,
                                     const int* __restrict__ initialized,
                                     const int* __restrict__ counts,
                                     float* __restrict__ out) {
    const int c = blockIdx.x;
    const int d = threadIdx.x;
    const int cntc = counts[c];
    const float sum = out[c * kD + d];

    const float mean   = sum / fmaxf((float)cntc, 1.0f);
    const float nrm    = sqrtf(block_sum256(mean * mean));
    const float mean_n = mean / fmaxf(nrm, kEps);

    const float p    = protos[c * kD + d];
    const float e    = kMom * p + (1.0f - kMom) * mean_n;
    const float nrm2 = sqrtf(block_sum256(e * e));
    const float ema  = e / fmaxf(nrm2, kEps);

    const float cand = (initialized[c] != 0) ? ema : mean_n;
    out[c * kD + d] = (cntc > 0) ? cand : p;
}

extern "C" void kernel_launch(void* const* d_in, const int* in_sizes, int n_in,
                              void* d_out, int out_size, void* d_ws, size_t ws_size,
                              hipStream_t stream) {
    const float* z           = (const float*)d_in[0];
    const float* protos      = (const float*)d_in[1];
    const int*   initialized = (const int*)d_in[2];
    const int*   labels      = (const int*)d_in[3];
    const int n = in_sizes[3];          // N (labels count)
    float* out = (float*)d_out;

    // ws layout (4-byte units):
    //   [cnt: 1024][ovf: 8 + 2N (count + pairs)][idx: kC*kCap]
    int* ws  = (int*)d_ws;
    int* cnt = ws;                          // [1024]
    int* ovf = ws + 1024;                   // [8 + 2N]
    int* idx = ws + 1024 + 8 + 2 * n;       // [kC*kCap]
    const size_t need = (size_t)(1024 + 8 + 2 * (size_t)n + (size_t)kC * kCap)
                        * sizeof(int);

    if (ws_size >= need) {
        // zero cnt + overflow count only (4.1 KB)
        (void)hipMemsetAsync(ws, 0, (size_t)(1024 + 8) * sizeof(int), stream);
        const int blocks = (n + 255) / 256;
        k_scatter<<<blocks, 256, 0, stream>>>(labels, n, cnt, idx, ovf);
        k_reduce <<<kC, kD, 0, stream>>>(z, protos, initialized, cnt, idx,
                                         ovf, out);
    } else {
        // fallback: accumulate sums directly in d_out with float atomics
        int* counts = ws;               // 4 KB
        (void)hipMemsetAsync(counts, 0, kC * sizeof(int), stream);
        (void)hipMemsetAsync(out, 0, (size_t)kC * kD * sizeof(float), stream);
        k_atomic_accum<<<n, kD, 0, stream>>>(z, labels, n, out, counts);
        k_finalize_from_sums<<<kC, kD, 0, stream>>>(protos, initialized, counts, out);
    }
}